// Round 5
// baseline (338.129 us; speedup 1.0000x reference)
//
#include <hip/hip_runtime.h>
#include <math.h>

#define HID 64
#define FD 32

// t-value schedule: 64 linspace(0.1, 1.1) samples then 64 exponential samples.
// Matched to the numpy reference: linspace evaluated in f64 then cast to f32
// (np.linspace semantics); exp evaluated as round_f32(exp_f64(arg_f32))
// (np.exp on f32 is correctly rounded; expf is not).
__device__ __forceinline__ float t_of(int i) {
    #pragma clang fp contract(off)
    if (i < 64) {
        if (i == 63) return 1.1f;                       // linspace endpoint exact
        return (float)(0.1 + (double)i * (1.0 / 63.0));
    }
    const float LOGC = 0.0038986404159402954f;          // float32(log(257/256))
    float arg = (float)(i - 64) * LOGC;                 // f32 multiply, like np
    return (float)exp((double)arg) * 1.1f;
}

// Occupancy test for one corner: valid && grid value == 1 (values are exactly 0/1).
__device__ __forceinline__ bool gv(const float* __restrict__ g, int zi, int yi, int xi) {
    bool ok = ((unsigned)zi < 128u) & ((unsigned)yi < 128u) & ((unsigned)xi < 128u);
    int zc = min(max(zi, 0), 127);
    int yc = min(max(yi, 0), 127);
    int xc = min(max(xi, 0), 127);
    float v = g[(((zc << 7) + yc) << 7) + xc];
    return ok & (v > 0.5f);
}

__global__ __launch_bounds__(256) void nerf_render(
    const float* __restrict__ rays_o, const float* __restrict__ rays_d,
    const float* __restrict__ grid,
    const float* __restrict__ W1,  const float* __restrict__ b1,
    const float* __restrict__ W2,  const float* __restrict__ b2,
    const float* __restrict__ Ws,  const float* __restrict__ bs,
    const float* __restrict__ Wr1, const float* __restrict__ br1,
    const float* __restrict__ Wr2, const float* __restrict__ br2,
    float* __restrict__ out)
{
    const int lane = threadIdx.x & 63;
    const int ray  = (blockIdx.x << 2) + (threadIdx.x >> 6);   // 4 waves/block, 1 ray/wave

    const float ox = rays_o[ray*3+0], oy = rays_o[ray*3+1], oz = rays_o[ray*3+2];
    const float dx = rays_d[ray*3+0], dy = rays_d[ray*3+1], dz = rays_d[ray*3+2];

    float rr = 0.f, rg = 0.f, rb = 0.f;
    float carry = 0.f;                 // running log-transmittance (wave-uniform)

    #pragma unroll 1
    for (int chunk = 0; chunk < 2; ++chunk) {
        const int s  = (chunk << 6) + lane;      // sample index; s==127 is padding
        const bool vs = (s < 127);
        const float tv = t_of(s);
        const float tn = t_of(s + 1);
        const float dist = tn - tv;

        float cx, cy, cz, fx, fy, fz;
        int x0, y0, z0;
        {
            // Match numpy elementwise rounding: no FMA contraction in the
            // geometry chain (mask depends on exact frac==0 decisions).
            #pragma clang fp contract(off)
            float px = ox + dx * tv;
            float py = oy + dy * tv;
            float pz = oz + dz * tv;
            float nrm = fmaxf(fabsf(px), fmaxf(fabsf(py), fabsf(pz)));
            if (nrm <= 1.0f) { cx = px; cy = py; cz = pz; }
            else {
                float t2 = 2.0f - 1.0f / nrm;
                cx = (t2 * px) / nrm; cy = (t2 * py) / nrm; cz = (t2 * pz) / nrm;
            }
            cx = cx * 0.5f; cy = cy * 0.5f; cz = cz * 0.5f;
            float gx = ((cx + 1.0f) * 128.0f - 1.0f) * 0.5f;
            float gy = ((cy + 1.0f) * 128.0f - 1.0f) * 0.5f;
            float gz = ((cz + 1.0f) * 128.0f - 1.0f) * 0.5f;
            float xf = floorf(gx), yf = floorf(gy), zf = floorf(gz);
            fx = gx - xf; fy = gy - yf; fz = gz - zf;
            x0 = (int)xf; y0 = (int)yf; z0 = (int)zf;
        }
        // occ > 0  <=>  some corner contributes a strictly positive term.
        // (grid values are exactly 0/1; (1-f) weights are always > 0, f sides need f > 0)
        const bool fxp = fx > 0.f, fyp = fy > 0.f, fzp = fz > 0.f;
        bool m = gv(grid, z0,   y0,   x0)
             | (fxp             & gv(grid, z0,   y0,   x0+1))
             | (fyp             & gv(grid, z0,   y0+1, x0))
             | (fyp & fxp       & gv(grid, z0,   y0+1, x0+1))
             | (fzp             & gv(grid, z0+1, y0,   x0))
             | (fzp & fxp       & gv(grid, z0+1, y0,   x0+1))
             | (fzp & fyp       & gv(grid, z0+1, y0+1, x0))
             | (fzp & fyp & fxp & gv(grid, z0+1, y0+1, x0+1));
        m = m & vs;

        const unsigned long long occb = __ballot(m);
        float feat[FD];
        if (occb) {                                   // wave-uniform branch
            // ---- density MLP: 3 -> 64 (relu) -> 32, fused (no h[] array) ----
            #pragma unroll
            for (int k = 0; k < FD; ++k) feat[k] = b2[k];
            #pragma unroll 4
            for (int j = 0; j < HID; ++j) {           // uniform idx -> scalar loads
                float h = b1[j];
                h = fmaf(cx, W1[j], h);
                h = fmaf(cy, W1[HID + j], h);
                h = fmaf(cz, W1[2*HID + j], h);
                h = fmaxf(h, 0.f);
                const float* w2r = W2 + j * FD;
                #pragma unroll
                for (int k = 0; k < FD; ++k) feat[k] = fmaf(h, w2r[k], feat[k]);
            }
            float sdot = bs[0];
            #pragma unroll
            for (int k = 0; k < FD; ++k) sdot = fmaf(feat[k], Ws[k], sdot);
            // jax.nn.softplus = max(x,0) + log1p(exp(-|x|))
            const float sp = fmaxf(sdot, 0.f) + log1pf(expf(-fabsf(sdot)));
            const float sigma = m ? sp : 0.f;
            const float al = -sigma * dist;

            // ---- inclusive wave scan of alpha_log (sample order = lane order) ----
            float xs = al;
            #pragma unroll
            for (int d = 1; d < 64; d <<= 1) {
                float y = __shfl_up(xs, (unsigned)d, 64);
                if (lane >= d) xs += y;
            }
            const float total = __shfl(xs, 63, 64);
            const float trans = expf(carry + (xs - al));   // exclusive prefix
            const float alpha = 1.0f - expf(al);
            const float w = trans * alpha;
            carry += total;

            const bool m2 = m & (w > 1e-4f);
            if (__ballot(m2)) {
                // ---- color MLP: 35 -> 64 (relu) -> 3 (sigmoid) ----
                float cr = br2[0], cg = br2[1], cb = br2[2];
                #pragma unroll 4
                for (int j = 0; j < HID; ++j) {
                    float h = br1[j];
                    #pragma unroll
                    for (int k = 0; k < FD; ++k) h = fmaf(feat[k], Wr1[k*HID + j], h);
                    h = fmaf(dx, Wr1[FD*HID + j], h);
                    h = fmaf(dy, Wr1[(FD+1)*HID + j], h);
                    h = fmaf(dz, Wr1[(FD+2)*HID + j], h);
                    h = fmaxf(h, 0.f);
                    cr = fmaf(h, Wr2[j*3+0], cr);
                    cg = fmaf(h, Wr2[j*3+1], cg);
                    cb = fmaf(h, Wr2[j*3+2], cb);
                }
                const float wm = m2 ? w : 0.f;
                rr = fmaf(1.f/(1.f + expf(-cr)), wm, rr);
                rg = fmaf(1.f/(1.f + expf(-cg)), wm, rg);
                rb = fmaf(1.f/(1.f + expf(-cb)), wm, rb);
            }
            // early termination: all later weights <= exp(carry) < 1e-4 (2x margin)
            if (chunk == 0 && expf(carry) <= 5e-5f) break;
        }
    }

    // sum rgb across the wave
    #pragma unroll
    for (int d = 32; d > 0; d >>= 1) {
        rr += __shfl_xor(rr, d, 64);
        rg += __shfl_xor(rg, d, 64);
        rb += __shfl_xor(rb, d, 64);
    }
    if (lane == 0) {
        out[ray*3+0] = rr;
        out[ray*3+1] = rg;
        out[ray*3+2] = rb;
    }
}

extern "C" void kernel_launch(void* const* d_in, const int* in_sizes, int n_in,
                              void* d_out, int out_size, void* d_ws, size_t ws_size,
                              hipStream_t stream) {
    const float* rays_o = (const float*)d_in[0];
    const float* rays_d = (const float*)d_in[1];
    const float* grid   = (const float*)d_in[2];
    const float* W1  = (const float*)d_in[3];
    const float* b1  = (const float*)d_in[4];
    const float* W2  = (const float*)d_in[5];
    const float* b2  = (const float*)d_in[6];
    const float* Ws  = (const float*)d_in[7];
    const float* bs  = (const float*)d_in[8];
    const float* Wr1 = (const float*)d_in[9];
    const float* br1 = (const float*)d_in[10];
    const float* Wr2 = (const float*)d_in[11];
    const float* br2 = (const float*)d_in[12];
    float* out = (float*)d_out;

    nerf_render<<<dim3(16384/4), dim3(256), 0, stream>>>(
        rays_o, rays_d, grid, W1, b1, W2, b2, Ws, bs, Wr1, br1, Wr2, br2, out);
}

// Round 10
// 317.299 us; speedup vs baseline: 1.0656x; 1.0656x over previous
//
#include <hip/hip_runtime.h>
#include <math.h>

#define HID 64
#define FD 32

typedef _Float16 h2_t __attribute__((ext_vector_type(2)));

// v_dot2_f32_f16: D = a.x*b.x + a.y*b.y + c  (fp16 mul, fp32 accumulate)
__device__ __forceinline__ float fdot2f(unsigned int a, unsigned int b, float c) {
    h2_t av = __builtin_bit_cast(h2_t, a);
    h2_t bv = __builtin_bit_cast(h2_t, b);
    return __builtin_amdgcn_fdot2(av, bv, c, false);
}
// v_cvt_pkrtz_f16_f32: pack two f32 -> half2 (round toward zero)
__device__ __forceinline__ unsigned int pk2(float a, float b) {
    auto v = __builtin_amdgcn_cvt_pkrtz(a, b);      // __fp16 ext_vector(2)
    return __builtin_bit_cast(unsigned int, v);
}

// ---- weight prep: repack W2 / Wr1 / Wr2 as half2 pairs along reduction dim ----
// ws layout (dwords): [0,1024): W2T   [k][i]   pair (W2[2i][k],  W2[2i+1][k])
//                     [1024,2304): Wr1p [j][20] pair (Wr1[2i][j], Wr1[2i+1][j]), k>=35 -> 0
//                     [2304,2400): Wr2p [c][32] pair (Wr2[2i][c], Wr2[2i+1][c])
__global__ void prep_weights(const float* __restrict__ W2,
                             const float* __restrict__ Wr1,
                             const float* __restrict__ Wr2,
                             unsigned int* __restrict__ ws) {
    int d = blockIdx.x * 256 + threadIdx.x;
    if (d >= 2400) return;
    float a = 0.f, b = 0.f;
    if (d < 1024) {
        int k = d >> 5, i = d & 31;
        a = W2[(2*i)   * FD + k];
        b = W2[(2*i+1) * FD + k];
    } else if (d < 2304) {
        int e = d - 1024, j = e / 20, i = e % 20;
        if (i < 18) {
            int k0 = 2*i, k1 = 2*i + 1;
            a = (k0 < 35) ? Wr1[k0 * HID + j] : 0.f;
            b = (k1 < 35) ? Wr1[k1 * HID + j] : 0.f;
        } else {
            ws[d] = 0u;
            return;
        }
    } else {
        int e = d - 2304, c = e >> 5, i = e & 31;
        a = Wr2[(2*i)   * 3 + c];
        b = Wr2[(2*i+1) * 3 + c];
    }
    h2_t v; v.x = (_Float16)a; v.y = (_Float16)b;    // RTN converts
    ws[d] = __builtin_bit_cast(unsigned int, v);
}

// t-value schedule matched to numpy (f64 linspace; correctly-rounded exp).
__device__ __forceinline__ float t_of(int i) {
    #pragma clang fp contract(off)
    if (i < 64) {
        if (i == 63) return 1.1f;
        return (float)(0.1 + (double)i * (1.0 / 63.0));
    }
    const float LOGC = 0.0038986404159402954f;          // float32(log(257/256))
    float arg = (float)(i - 64) * LOGC;
    return (float)exp((double)arg) * 1.1f;
}

__device__ __forceinline__ bool gv(const float* __restrict__ g, int zi, int yi, int xi) {
    bool ok = ((unsigned)zi < 128u) & ((unsigned)yi < 128u) & ((unsigned)xi < 128u);
    int zc = min(max(zi, 0), 127);
    int yc = min(max(yi, 0), 127);
    int xc = min(max(xi, 0), 127);
    float v = g[(((zc << 7) + yc) << 7) + xc];
    return ok & (v > 0.5f);
}

__global__ __launch_bounds__(256) void nerf_render(
    const float* __restrict__ rays_o, const float* __restrict__ rays_d,
    const float* __restrict__ grid,
    const float* __restrict__ W1,  const float* __restrict__ b1,
    const float* __restrict__ b2,
    const float* __restrict__ Ws,  const float* __restrict__ bs,
    const float* __restrict__ br1, const float* __restrict__ br2,
    const unsigned int* __restrict__ wsp,
    float* __restrict__ out)
{
    const int lane = threadIdx.x & 63;
    const int ray  = (blockIdx.x << 2) + (threadIdx.x >> 6);   // 4 waves/block, 1 ray/wave

    const unsigned int* w2t  = wsp;          // [32][32]
    const unsigned int* wr1p = wsp + 1024;   // [64][20]
    const unsigned int* wr2p = wsp + 2304;   // [3][32]

    const float ox = rays_o[ray*3+0], oy = rays_o[ray*3+1], oz = rays_o[ray*3+2];
    const float dx = rays_d[ray*3+0], dy = rays_d[ray*3+1], dz = rays_d[ray*3+2];
    const unsigned int d01 = pk2(dx, dy);
    const unsigned int d23 = pk2(dz, 0.f);

    float rr = 0.f, rg = 0.f, rb = 0.f;
    float carry = 0.f;                 // running log-transmittance (wave-uniform)

    #pragma unroll 1
    for (int chunk = 0; chunk < 2; ++chunk) {
        const int s  = (chunk << 6) + lane;      // sample index; s==127 is padding
        const bool vs = (s < 127);
        const float tv = t_of(s);
        const float tn = t_of(s + 1);
        const float dist = tn - tv;

        float cx, cy, cz, fx, fy, fz;
        int x0, y0, z0;
        {
            // Exact fp32 geometry: no FMA contraction (mask depends on floor/frac).
            #pragma clang fp contract(off)
            float px = ox + dx * tv;
            float py = oy + dy * tv;
            float pz = oz + dz * tv;
            float nrm = fmaxf(fabsf(px), fmaxf(fabsf(py), fabsf(pz)));
            if (nrm <= 1.0f) { cx = px; cy = py; cz = pz; }
            else {
                float t2 = 2.0f - 1.0f / nrm;
                cx = (t2 * px) / nrm; cy = (t2 * py) / nrm; cz = (t2 * pz) / nrm;
            }
            cx = cx * 0.5f; cy = cy * 0.5f; cz = cz * 0.5f;
            float gx = ((cx + 1.0f) * 128.0f - 1.0f) * 0.5f;
            float gy = ((cy + 1.0f) * 128.0f - 1.0f) * 0.5f;
            float gz = ((cz + 1.0f) * 128.0f - 1.0f) * 0.5f;
            float xf = floorf(gx), yf = floorf(gy), zf = floorf(gz);
            fx = gx - xf; fy = gy - yf; fz = gz - zf;
            x0 = (int)xf; y0 = (int)yf; z0 = (int)zf;
        }
        const bool fxp = fx > 0.f, fyp = fy > 0.f, fzp = fz > 0.f;
        bool m = gv(grid, z0,   y0,   x0)
             | (fxp             & gv(grid, z0,   y0,   x0+1))
             | (fyp             & gv(grid, z0,   y0+1, x0))
             | (fyp & fxp       & gv(grid, z0,   y0+1, x0+1))
             | (fzp             & gv(grid, z0+1, y0,   x0))
             | (fzp & fxp       & gv(grid, z0+1, y0,   x0+1))
             | (fzp & fyp       & gv(grid, z0+1, y0+1, x0))
             | (fzp & fyp & fxp & gv(grid, z0+1, y0+1, x0+1));
        m = m & vs;

        const unsigned long long occb = __ballot(m);
        if (occb) {                                   // wave-uniform branch
            // ---- density layer 1 (fp32) -> h packed to half2 ----
            unsigned int hpk[HID/2];
            {
                float hprev = 0.f;
                #pragma unroll 4
                for (int j = 0; j < HID; ++j) {
                    float h = b1[j];
                    h = fmaf(cx, W1[j], h);
                    h = fmaf(cy, W1[HID + j], h);
                    h = fmaf(cz, W1[2*HID + j], h);
                    h = fmaxf(h, 0.f);
                    if (j & 1) hpk[j >> 1] = pk2(hprev, h); else hprev = h;
                }
            }
            // ---- density layer 2 via fdot2; sigma dot kept fp32 ----
            unsigned int featpk[FD/2];
            float sdot = bs[0];
            {
                float fprev = 0.f;
                #pragma unroll 2
                for (int k = 0; k < FD; ++k) {
                    float a = b2[k];
                    const unsigned int* row = w2t + k * 32;
                    #pragma unroll
                    for (int i = 0; i < 32; ++i) a = fdot2f(hpk[i], row[i], a);
                    sdot = fmaf(a, Ws[k], sdot);
                    if (k & 1) featpk[k >> 1] = pk2(fprev, a); else fprev = a;
                }
            }
            // jax.nn.softplus = max(x,0) + log1p(exp(-|x|))
            const float sp = fmaxf(sdot, 0.f) + log1pf(expf(-fabsf(sdot)));
            const float sigma = m ? sp : 0.f;
            const float al = -sigma * dist;

            // ---- inclusive wave scan of alpha_log ----
            float xs = al;
            #pragma unroll
            for (int d = 1; d < 64; d <<= 1) {
                float y = __shfl_up(xs, (unsigned)d, 64);
                if (lane >= d) xs += y;
            }
            const float total = __shfl(xs, 63, 64);
            const float trans = expf(carry + (xs - al));   // exclusive prefix
            const float alpha = 1.0f - expf(al);
            const float w = trans * alpha;
            carry += total;

            const bool m2 = m & (w > 1e-4f);
            if (__ballot(m2)) {
                // ---- color MLP: [feat(32); dirs(3)] -> 64 relu -> 3 sigmoid ----
                unsigned int h2pk[HID/2];
                {
                    float hp = 0.f;
                    #pragma unroll 2
                    for (int j = 0; j < HID; ++j) {
                        float a = br1[j];
                        const unsigned int* row = wr1p + j * 20;
                        #pragma unroll
                        for (int i = 0; i < 16; ++i) a = fdot2f(featpk[i], row[i], a);
                        a = fdot2f(d01, row[16], a);
                        a = fdot2f(d23, row[17], a);
                        a = fmaxf(a, 0.f);
                        if (j & 1) h2pk[j >> 1] = pk2(hp, a); else hp = a;
                    }
                }
                float lgt[3];
                #pragma unroll
                for (int c = 0; c < 3; ++c) {
                    float a = br2[c];
                    const unsigned int* row = wr2p + c * 32;
                    #pragma unroll
                    for (int i = 0; i < 32; ++i) a = fdot2f(h2pk[i], row[i], a);
                    lgt[c] = a;
                }
                const float wm = m2 ? w : 0.f;
                rr = fmaf(1.f/(1.f + expf(-lgt[0])), wm, rr);
                rg = fmaf(1.f/(1.f + expf(-lgt[1])), wm, rg);
                rb = fmaf(1.f/(1.f + expf(-lgt[2])), wm, rb);
            }
            // early termination: all later weights <= exp(carry) < 1e-4 (2x margin)
            if (chunk == 0 && expf(carry) <= 5e-5f) break;
        }
    }

    #pragma unroll
    for (int d = 32; d > 0; d >>= 1) {
        rr += __shfl_xor(rr, d, 64);
        rg += __shfl_xor(rg, d, 64);
        rb += __shfl_xor(rb, d, 64);
    }
    if (lane == 0) {
        out[ray*3+0] = rr;
        out[ray*3+1] = rg;
        out[ray*3+2] = rb;
    }
}

extern "C" void kernel_launch(void* const* d_in, const int* in_sizes, int n_in,
                              void* d_out, int out_size, void* d_ws, size_t ws_size,
                              hipStream_t stream) {
    const float* rays_o = (const float*)d_in[0];
    const float* rays_d = (const float*)d_in[1];
    const float* grid   = (const float*)d_in[2];
    const float* W1  = (const float*)d_in[3];
    const float* b1  = (const float*)d_in[4];
    const float* W2  = (const float*)d_in[5];
    const float* b2  = (const float*)d_in[6];
    const float* Ws  = (const float*)d_in[7];
    const float* bs  = (const float*)d_in[8];
    const float* Wr1 = (const float*)d_in[9];
    const float* br1 = (const float*)d_in[10];
    const float* Wr2 = (const float*)d_in[11];
    const float* br2 = (const float*)d_in[12];
    float* out = (float*)d_out;
    unsigned int* ws = (unsigned int*)d_ws;

    prep_weights<<<dim3(10), dim3(256), 0, stream>>>(W2, Wr1, Wr2, ws);
    nerf_render<<<dim3(16384/4), dim3(256), 0, stream>>>(
        rays_o, rays_d, grid, W1, b1, b2, Ws, bs, br1, br2, ws, out);
}

// Round 11
// 192.675 us; speedup vs baseline: 1.7549x; 1.6468x over previous
//
#include <hip/hip_runtime.h>
#include <math.h>

#define HID 64
#define FD 32
#define ROWB 144   // LDS row pitch bytes (72 f16) -> 2-way bank conflicts only

typedef __fp16 f16x8 __attribute__((ext_vector_type(8)));
typedef float  f32x4 __attribute__((ext_vector_type(4)));
typedef unsigned int u32x4 __attribute__((ext_vector_type(4)));
typedef unsigned int u32x2 __attribute__((ext_vector_type(2)));

__device__ __forceinline__ unsigned int pk2(float a, float b) {
    auto v = __builtin_amdgcn_cvt_pkrtz(a, b);
    return __builtin_bit_cast(unsigned int, v);
}
__device__ __forceinline__ f32x4 mfma16(f16x8 a, f16x8 b, f32x4 c) {
    return __builtin_amdgcn_mfma_f32_16x16x32_f16(a, b, c, 0, 0, 0);
}

// ---- prep: weight^T A-fragments (f16, MFMA A-layout) + extended bias ----
// ws: [0,16384): 16 frags x 64 lanes x 16B
//   0..5  : L2  A=[W2 | wv | 0]^T (M=48,K=64), idx=mt*2+kc
//   6..13 : cL1 A=Wr1^T zero-pad  (M=64,K=64), idx=6+mt*2+kc
//   14..15: cL2 A=Wr2^T zero-pad  (M=16,K=64), idx=14+kc
// [16384,16576): b2e[48] f32 = [b2 | b2.Ws+bs | 0]
__global__ void prep(const float* __restrict__ W2,  const float* __restrict__ Ws,
                     const float* __restrict__ bs,  const float* __restrict__ b2,
                     const float* __restrict__ Wr1, const float* __restrict__ Wr2,
                     unsigned char* __restrict__ wsb) {
    __shared__ float wv[64];
    const int t = threadIdx.x;                 // 1024 threads, 1 block
    if (t < 64) {
        float acc = 0.f;
        for (int k = 0; k < FD; ++k) acc = fmaf(W2[t*FD+k], Ws[k], acc);
        wv[t] = acc;
    }
    __syncthreads();
    if (t < 48) {
        float v = 0.f;
        if (t < 32) v = b2[t];
        else if (t == 32) {
            float c = bs[0];
            for (int k = 0; k < FD; ++k) c = fmaf(b2[k], Ws[k], c);
            v = c;
        }
        ((float*)(wsb + 16384))[t] = v;
    }
    const int f = t >> 6, lane = t & 63;
    const int c15 = lane & 15, g = lane >> 4;
    f16x8 o;
    #pragma unroll
    for (int j = 0; j < 8; ++j) {
        float v = 0.f;
        if (f < 6) {
            int mt = f >> 1, kc = f & 1, row = 16*mt + c15;
            int kg = 32*kc + 8*g + j;
            v = (row < 32) ? W2[kg*FD + row] : ((row == 32) ? wv[kg] : 0.f);
        } else if (f < 14) {
            int ff = f - 6, mt = ff >> 1, kc = ff & 1, row = 16*mt + c15;
            int kg = 32*kc + 8*g + j;
            v = (kg < FD+3) ? Wr1[kg*HID + row] : 0.f;
        } else {
            int kc = f - 14, row = c15;
            int kg = 32*kc + 8*g + j;
            v = (row < 3) ? Wr2[kg*3 + row] : 0.f;
        }
        o[j] = (__fp16)v;
    }
    *(f16x8*)(wsb + (f*64 + lane)*16) = o;
}

// t-schedule matched to numpy (f64 linspace; correctly-rounded exp)
__device__ __forceinline__ float t_of(int i) {
    #pragma clang fp contract(off)
    if (i < 64) {
        if (i == 63) return 1.1f;
        return (float)(0.1 + (double)i * (1.0 / 63.0));
    }
    const float LOGC = 0.0038986404159402954f;
    float arg = (float)(i - 64) * LOGC;
    return (float)exp((double)arg) * 1.1f;
}

__device__ __forceinline__ bool gv(const float* __restrict__ g, int zi, int yi, int xi) {
    bool ok = ((unsigned)zi < 128u) & ((unsigned)yi < 128u) & ((unsigned)xi < 128u);
    int zc = min(max(zi, 0), 127);
    int yc = min(max(yi, 0), 127);
    int xc = min(max(xi, 0), 127);
    float v = g[(((zc << 7) + yc) << 7) + xc];
    return ok & (v > 0.5f);
}

__global__ __launch_bounds__(256) void nerf_render(
    const float* __restrict__ rays_o, const float* __restrict__ rays_d,
    const float* __restrict__ grid,
    const float* __restrict__ W1,  const float* __restrict__ b1,
    const float* __restrict__ br1, const float* __restrict__ br2,
    const unsigned char* __restrict__ wsb,
    float* __restrict__ out)
{
    __shared__ unsigned char lds[40960] __attribute__((aligned(16)));
    const int lane = threadIdx.x & 63;
    const int wid  = threadIdx.x >> 6;
    const int ray  = (blockIdx.x << 2) + wid;
    const int c15 = lane & 15, g = lane >> 4;

    unsigned char* ldsH = lds + wid*10240;                 // [64 rows][72 f16]
    float* ldsSig = (float*)(lds + wid*10240 + 9216);      // [64]
    float* ldsRgb = (float*)(lds + wid*10240 + 9472);      // [64][3]

    const f16x8* AF  = (const f16x8*)wsb;
    const float* b2e = (const float*)(wsb + 16384);

    const float ox = rays_o[ray*3+0], oy = rays_o[ray*3+1], oz = rays_o[ray*3+2];
    const float dx = rays_d[ray*3+0], dy = rays_d[ray*3+1], dz = rays_d[ray*3+2];

    f16x8 bd;                                   // dirs B-frag (kc=1 of color L1)
    #pragma unroll
    for (int j = 0; j < 8; ++j) bd[j] = (__fp16)0.f;
    if (g == 0) { bd[0] = (__fp16)dx; bd[1] = (__fp16)dy; bd[2] = (__fp16)dz; }

    float rr = 0.f, rg = 0.f, rb = 0.f;
    float carry = 0.f;

    #pragma unroll 1
    for (int chunk = 0; chunk < 2; ++chunk) {
        const int s  = (chunk << 6) + lane;
        const bool vs = (s < 127);
        const float tv = t_of(s);
        const float tn = t_of(s + 1);
        const float dist = tn - tv;

        float cx, cy, cz, fx, fy, fz;
        int x0, y0, z0;
        {
            #pragma clang fp contract(off)
            float px = ox + dx * tv;
            float py = oy + dy * tv;
            float pz = oz + dz * tv;
            float nrm = fmaxf(fabsf(px), fmaxf(fabsf(py), fabsf(pz)));
            if (nrm <= 1.0f) { cx = px; cy = py; cz = pz; }
            else {
                float t2 = 2.0f - 1.0f / nrm;
                cx = (t2 * px) / nrm; cy = (t2 * py) / nrm; cz = (t2 * pz) / nrm;
            }
            cx = cx * 0.5f; cy = cy * 0.5f; cz = cz * 0.5f;
            float gx = ((cx + 1.0f) * 128.0f - 1.0f) * 0.5f;
            float gy = ((cy + 1.0f) * 128.0f - 1.0f) * 0.5f;
            float gz = ((cz + 1.0f) * 128.0f - 1.0f) * 0.5f;
            float xf = floorf(gx), yf = floorf(gy), zf = floorf(gz);
            fx = gx - xf; fy = gy - yf; fz = gz - zf;
            x0 = (int)xf; y0 = (int)yf; z0 = (int)zf;
        }
        const bool fxp = fx > 0.f, fyp = fy > 0.f, fzp = fz > 0.f;
        bool m = gv(grid, z0,   y0,   x0)
             | (fxp             & gv(grid, z0,   y0,   x0+1))
             | (fyp             & gv(grid, z0,   y0+1, x0))
             | (fyp & fxp       & gv(grid, z0,   y0+1, x0+1))
             | (fzp             & gv(grid, z0+1, y0,   x0))
             | (fzp & fxp       & gv(grid, z0+1, y0,   x0+1))
             | (fzp & fyp       & gv(grid, z0+1, y0+1, x0))
             | (fzp & fyp & fxp & gv(grid, z0+1, y0+1, x0+1));
        m = m & vs;

        if (__ballot(m)) {
            // ---- L1 per-lane fp32 (3->64 relu), write H row to LDS as f16 ----
            {
                unsigned char* hw = ldsH + lane*ROWB;
                #pragma unroll
                for (int i = 0; i < 8; ++i) {
                    u32x4 wq;
                    #pragma unroll
                    for (int p = 0; p < 4; ++p) {
                        const int j0 = i*8 + p*2;
                        float h0 = b1[j0];
                        h0 = fmaf(cx, W1[j0], h0);
                        h0 = fmaf(cy, W1[HID + j0], h0);
                        h0 = fmaf(cz, W1[2*HID + j0], h0);
                        h0 = fmaxf(h0, 0.f);
                        float h1 = b1[j0+1];
                        h1 = fmaf(cx, W1[j0+1], h1);
                        h1 = fmaf(cy, W1[HID + j0+1], h1);
                        h1 = fmaf(cz, W1[2*HID + j0+1], h1);
                        h1 = fmaxf(h1, 0.f);
                        wq[p] = pk2(h0, h1);
                    }
                    *(u32x4*)(hw + i*16) = wq;
                }
            }
            // ---- read H^T B-fragments (same wave wrote them; DS is in-order) ----
            f16x8 bh[4][2];
            #pragma unroll
            for (int nt = 0; nt < 4; ++nt)
                #pragma unroll
                for (int kc = 0; kc < 2; ++kc)
                    bh[nt][kc] = *(const f16x8*)(ldsH + (16*nt + c15)*ROWB + 64*kc + 16*g);

            // per-column (sample) mask gather
            float mfv[4];
            {
                int mi = __builtin_bit_cast(int, m ? 1.f : 0.f);
                #pragma unroll
                for (int nt = 0; nt < 4; ++nt)
                    mfv[nt] = __builtin_bit_cast(float,
                        __builtin_amdgcn_ds_bpermute((16*nt + c15) << 2, mi));
            }

            // ---- L2: F^T = W2e^T H^T + b2e  (row 32 = sigma_pre, fused) ----
            #pragma unroll
            for (int mt = 0; mt < 3; ++mt) {
                f16x8 a0 = AF[(mt*2+0)*64 + lane];
                f16x8 a1 = AF[(mt*2+1)*64 + lane];
                f32x4 acc[4];
                #pragma unroll
                for (int nt = 0; nt < 4; ++nt) { f32x4 z = {0.f,0.f,0.f,0.f}; acc[nt] = z; }
                #pragma unroll
                for (int nt = 0; nt < 4; ++nt) acc[nt] = mfma16(a0, bh[nt][0], acc[nt]);
                #pragma unroll
                for (int nt = 0; nt < 4; ++nt) acc[nt] = mfma16(a1, bh[nt][1], acc[nt]);
                f32x4 bb = *(const f32x4*)(b2e + 16*mt + 4*g);
                if (mt < 2) {
                    #pragma unroll
                    for (int nt = 0; nt < 4; ++nt) {
                        float v0 = (acc[nt][0] + bb[0]) * mfv[nt];
                        float v1 = (acc[nt][1] + bb[1]) * mfv[nt];
                        float v2 = (acc[nt][2] + bb[2]) * mfv[nt];
                        float v3 = (acc[nt][3] + bb[3]) * mfv[nt];
                        u32x2 w2; w2[0] = pk2(v0, v1); w2[1] = pk2(v2, v3);
                        *(u32x2*)(ldsH + (16*nt + c15)*ROWB + 32*mt + 8*g) = w2;
                    }
                } else if (g == 0) {
                    #pragma unroll
                    for (int nt = 0; nt < 4; ++nt)
                        ldsSig[16*nt + c15] = acc[nt][0] + bb[0];
                }
            }
            const float spre = ldsSig[lane];
            const float sp = fmaxf(spre, 0.f) + log1pf(expf(-fabsf(spre)));
            const float sigma = m ? sp : 0.f;
            const float al = -sigma * dist;

            // ---- inclusive wave scan of alpha_log ----
            float xs = al;
            #pragma unroll
            for (int d = 1; d < 64; d <<= 1) {
                float y = __shfl_up(xs, (unsigned)d, 64);
                if (lane >= d) xs += y;
            }
            const float total = __shfl(xs, 63, 64);
            const float trans = expf(carry + (xs - al));
            const float alpha = 1.0f - expf(al);
            const float w = trans * alpha;
            carry += total;

            const bool m2 = m & (w > 1e-4f);
            if (__ballot(m2)) {
                // ---- color L1: H2^T = relu(Wr1^T [F;dirs]^T + br1) ----
                f16x8 bf[4];
                #pragma unroll
                for (int nt = 0; nt < 4; ++nt)
                    bf[nt] = *(const f16x8*)(ldsH + (16*nt + c15)*ROWB + 16*g);
                #pragma unroll
                for (int mt = 0; mt < 4; ++mt) {
                    f16x8 a0 = AF[(6 + mt*2 + 0)*64 + lane];
                    f16x8 a1 = AF[(6 + mt*2 + 1)*64 + lane];
                    f32x4 acc[4];
                    #pragma unroll
                    for (int nt = 0; nt < 4; ++nt) { f32x4 z = {0.f,0.f,0.f,0.f}; acc[nt] = z; }
                    #pragma unroll
                    for (int nt = 0; nt < 4; ++nt) acc[nt] = mfma16(a0, bf[nt], acc[nt]);
                    #pragma unroll
                    for (int nt = 0; nt < 4; ++nt) acc[nt] = mfma16(a1, bd, acc[nt]);
                    f32x4 bb = *(const f32x4*)(br1 + 16*mt + 4*g);
                    #pragma unroll
                    for (int nt = 0; nt < 4; ++nt) {
                        float v0 = fmaxf(acc[nt][0] + bb[0], 0.f);
                        float v1 = fmaxf(acc[nt][1] + bb[1], 0.f);
                        float v2 = fmaxf(acc[nt][2] + bb[2], 0.f);
                        float v3 = fmaxf(acc[nt][3] + bb[3], 0.f);
                        u32x2 w2; w2[0] = pk2(v0, v1); w2[1] = pk2(v2, v3);
                        *(u32x2*)(ldsH + (16*nt + c15)*ROWB + 32*mt + 8*g) = w2;
                    }
                }
                // ---- color L2: RGB^T = Wr2^T H2^T ----
                f16x8 a0 = AF[14*64 + lane];
                f16x8 a1 = AF[15*64 + lane];
                f32x4 accr[4];
                #pragma unroll
                for (int nt = 0; nt < 4; ++nt) {
                    f16x8 q0 = *(const f16x8*)(ldsH + (16*nt + c15)*ROWB + 16*g);
                    f16x8 q1 = *(const f16x8*)(ldsH + (16*nt + c15)*ROWB + 64 + 16*g);
                    f32x4 z = {0.f,0.f,0.f,0.f};
                    z = mfma16(a0, q0, z);
                    z = mfma16(a1, q1, z);
                    accr[nt] = z;
                }
                if (g == 0) {
                    const float c0 = br2[0], c1 = br2[1], c2 = br2[2];
                    #pragma unroll
                    for (int nt = 0; nt < 4; ++nt) {
                        float* rp = ldsRgb + (16*nt + c15)*3;
                        rp[0] = accr[nt][0] + c0;
                        rp[1] = accr[nt][1] + c1;
                        rp[2] = accr[nt][2] + c2;
                    }
                }
                const float* rp = ldsRgb + lane*3;
                const float l0 = rp[0], l1 = rp[1], l2 = rp[2];
                const float wm = m2 ? w : 0.f;
                rr = fmaf(1.f/(1.f + expf(-l0)), wm, rr);
                rg = fmaf(1.f/(1.f + expf(-l1)), wm, rg);
                rb = fmaf(1.f/(1.f + expf(-l2)), wm, rb);
            }
            if (chunk == 0 && expf(carry) <= 5e-5f) break;
        }
    }

    #pragma unroll
    for (int d = 32; d > 0; d >>= 1) {
        rr += __shfl_xor(rr, d, 64);
        rg += __shfl_xor(rg, d, 64);
        rb += __shfl_xor(rb, d, 64);
    }
    if (lane == 0) {
        out[ray*3+0] = rr;
        out[ray*3+1] = rg;
        out[ray*3+2] = rb;
    }
}

extern "C" void kernel_launch(void* const* d_in, const int* in_sizes, int n_in,
                              void* d_out, int out_size, void* d_ws, size_t ws_size,
                              hipStream_t stream) {
    const float* rays_o = (const float*)d_in[0];
    const float* rays_d = (const float*)d_in[1];
    const float* grid   = (const float*)d_in[2];
    const float* W1  = (const float*)d_in[3];
    const float* b1  = (const float*)d_in[4];
    const float* W2  = (const float*)d_in[5];
    const float* b2  = (const float*)d_in[6];
    const float* Ws  = (const float*)d_in[7];
    const float* bs  = (const float*)d_in[8];
    const float* Wr1 = (const float*)d_in[9];
    const float* br1 = (const float*)d_in[10];
    const float* Wr2 = (const float*)d_in[11];
    const float* br2 = (const float*)d_in[12];
    float* out = (float*)d_out;
    unsigned char* ws = (unsigned char*)d_ws;

    prep<<<dim3(1), dim3(1024), 0, stream>>>(W2, Ws, bs, b2, Wr1, Wr2, ws);
    nerf_render<<<dim3(16384/4), dim3(256), 0, stream>>>(
        rays_o, rays_d, grid, W1, b1, br1, br2, ws, out);
}

// Round 12
// 175.842 us; speedup vs baseline: 1.9229x; 1.0957x over previous
//
#include <hip/hip_runtime.h>
#include <math.h>

#define HID 64
#define FD 32
#define ROWB 144   // LDS row pitch bytes

typedef __fp16 f16x8 __attribute__((ext_vector_type(8)));
typedef __fp16 f16x2v __attribute__((ext_vector_type(2)));
typedef float  f32x4 __attribute__((ext_vector_type(4)));
typedef unsigned int u32x4 __attribute__((ext_vector_type(4)));
typedef unsigned int u32x2 __attribute__((ext_vector_type(2)));

__device__ __forceinline__ unsigned int pk2(float a, float b) {
    auto v = __builtin_amdgcn_cvt_pkrtz(a, b);
    return __builtin_bit_cast(unsigned int, v);
}
__device__ __forceinline__ unsigned int pkadd(unsigned int a, unsigned int b) {
    f16x2v x = __builtin_bit_cast(f16x2v, a), y = __builtin_bit_cast(f16x2v, b);
    f16x2v r = x + y;
    return __builtin_bit_cast(unsigned int, r);
}
__device__ __forceinline__ unsigned int pkmax0(unsigned int a) {
    f16x2v x = __builtin_bit_cast(f16x2v, a);
    f16x2v z = {(__fp16)0.f, (__fp16)0.f};
    f16x2v r = __builtin_elementwise_max(x, z);
    return __builtin_bit_cast(unsigned int, r);
}
__device__ __forceinline__ f32x4 mfma16(f16x8 a, f16x8 b, f32x4 c) {
    return __builtin_amdgcn_mfma_f32_16x16x32_f16(a, b, c, 0, 0, 0);
}

// t-schedule matched to numpy (f64 linspace; correctly-rounded exp). Prep-only.
__device__ __forceinline__ float t_of(int i) {
    #pragma clang fp contract(off)
    if (i < 64) {
        if (i == 63) return 1.1f;
        return (float)(0.1 + (double)i * (1.0 / 63.0));
    }
    const float LOGC = 0.0038986404159402954f;
    float arg = (float)(i - 64) * LOGC;
    return (float)exp((double)arg) * 1.1f;
}

// ws layout (bytes):
//   [0,20480)      : 20 A-frags x 64 lanes x 16B  (f16 MFMA A-layout)
//     0..5  : L2  A=[W2 | W2.Ws | 0]^T (M=48,K=64), idx=mt*2+kc
//     6..13 : cL1 A=Wr1^T zero-pad     (M=64,K=64), idx=6+mt*2+kc
//     14..15: cL2 A=Wr2^T zero-pad     (M=16,K=64), idx=14+kc
//     16..19: L1  A=[W1hi|W1lo|b1|0]^T (M=64,K=32), idx=16+mt
//   [20480,20672)  : b2e[48] f32 = [b2 | b2.Ws+bs | 0]
//   [20672,20736)  : fpk[16]  u32 = b2 f16-pairs   [mt<2][g][p]
//   [20736,20864)  : r1pk[32] u32 = br1 f16-pairs  [mt<4][g][p]
//   [20864,21376)  : ttab[128] f32
//   [21376,21888)  : dtab[128] f32
__global__ void prep(const float* __restrict__ W1, const float* __restrict__ b1,
                     const float* __restrict__ W2, const float* __restrict__ b2,
                     const float* __restrict__ Ws, const float* __restrict__ bs,
                     const float* __restrict__ Wr1, const float* __restrict__ br1,
                     const float* __restrict__ Wr2,
                     unsigned char* __restrict__ wsb) {
    __shared__ float wv[64];
    const int t = threadIdx.x;                 // 1024 threads, 1 block
    if (t < 64) {
        float acc = 0.f;
        for (int k = 0; k < FD; ++k) acc = fmaf(W2[t*FD+k], Ws[k], acc);
        wv[t] = acc;
    }
    __syncthreads();
    float* b2e = (float*)(wsb + 20480);
    unsigned int* fpk  = (unsigned int*)(wsb + 20672);
    unsigned int* r1pk = (unsigned int*)(wsb + 20736);
    float* ttab = (float*)(wsb + 20864);
    float* dtab = (float*)(wsb + 21376);
    if (t < 48) {
        float v = 0.f;
        if (t < 32) v = b2[t];
        else if (t == 32) {
            float c = bs[0];
            for (int k = 0; k < FD; ++k) c = fmaf(b2[k], Ws[k], c);
            v = c;
        }
        b2e[t] = v;
    }
    if (t >= 64 && t < 192) { int s = t - 64; ttab[s] = t_of(s); dtab[s] = t_of(s+1) - t_of(s); }
    if (t >= 192 && t < 208) {
        int e = t - 192, mt = e >> 3, g = (e >> 1) & 3, p = e & 1;
        int row = 16*mt + 4*g + 2*p;
        fpk[e] = pk2(b2[row], b2[row+1]);
    }
    if (t >= 208 && t < 240) {
        int e = t - 208, mt = e >> 3, g = (e >> 1) & 3, p = e & 1;
        int row = 16*mt + 4*g + 2*p;
        r1pk[e] = pk2(br1[row], br1[row+1]);
    }
    const int f = t >> 6, lane = t & 63;
    const int c15 = lane & 15, g = lane >> 4;
    f16x8 o;
    #pragma unroll
    for (int j = 0; j < 8; ++j) {
        float v = 0.f;
        if (f < 6) {
            int mt = f >> 1, kc = f & 1, row = 16*mt + c15;
            int kg = 32*kc + 8*g + j;
            v = (row < 32) ? W2[kg*FD + row] : ((row == 32) ? wv[kg] : 0.f);
        } else if (f < 14) {
            int ff = f - 6, mt = ff >> 1, kc = ff & 1, row = 16*mt + c15;
            int kg = 32*kc + 8*g + j;
            v = (kg < FD+3) ? Wr1[kg*HID + row] : 0.f;
        } else {
            int kc = f - 14, row = c15;
            int kg = 32*kc + 8*g + j;
            v = (row < 3) ? Wr2[kg*3 + row] : 0.f;
        }
        o[j] = (__fp16)v;
    }
    *(f16x8*)(wsb + (f*64 + lane)*16) = o;
    if (f < 4) {                                // L1 A-frag 16+f (mt=f)
        f16x8 o2;
        #pragma unroll
        for (int j = 0; j < 8; ++j) {
            int row = 16*f + c15, k = 8*g + j;
            float v = 0.f;
            if (k < 3)       v = W1[k*HID + row];
            else if (k < 6)  v = W1[(k-3)*HID + row];
            else if (k == 6) v = b1[row];
            o2[j] = (__fp16)v;
        }
        *(f16x8*)(wsb + ((16+f)*64 + lane)*16) = o2;
    }
}

__device__ __forceinline__ bool gv(const float* __restrict__ g, int zi, int yi, int xi) {
    bool ok = ((unsigned)zi < 128u) & ((unsigned)yi < 128u) & ((unsigned)xi < 128u);
    int zc = min(max(zi, 0), 127);
    int yc = min(max(yi, 0), 127);
    int xc = min(max(xi, 0), 127);
    float v = g[(((zc << 7) + yc) << 7) + xc];
    return ok & (v > 0.5f);
}

__global__ __launch_bounds__(256) void nerf_render(
    const float* __restrict__ rays_o, const float* __restrict__ rays_d,
    const float* __restrict__ grid,  const float* __restrict__ br2,
    const unsigned char* __restrict__ wsb,
    float* __restrict__ out)
{
    __shared__ unsigned char lds[40960] __attribute__((aligned(16)));
    const int lane = threadIdx.x & 63;
    const int wid  = threadIdx.x >> 6;
    const int ray  = (blockIdx.x << 2) + wid;
    const int c15 = lane & 15, g = lane >> 4;

    unsigned char* ldsH = lds + wid*10240;                 // [64 rows][ROWB]
    float* ldsSig = (float*)(lds + wid*10240 + 9216);      // [64]
    float* ldsRgb = (float*)(lds + wid*10240 + 9472);      // [64][3]

    const f16x8* AF = (const f16x8*)wsb;
    const float* b2e = (const float*)(wsb + 20480);
    const unsigned int* fpk  = (const unsigned int*)(wsb + 20672);
    const unsigned int* r1pk = (const unsigned int*)(wsb + 20736);
    const float* ttab = (const float*)(wsb + 20864);
    const float* dtab = (const float*)(wsb + 21376);

    const float ox = rays_o[ray*3+0], oy = rays_o[ray*3+1], oz = rays_o[ray*3+2];
    const float dx = rays_d[ray*3+0], dy = rays_d[ray*3+1], dz = rays_d[ray*3+2];

    // hoisted per-lane constants
    const float b2e32 = b2e[32];
    unsigned int fpkv[2][2], r1pkv[4][2];
    #pragma unroll
    for (int mt = 0; mt < 2; ++mt) { fpkv[mt][0] = fpk[mt*8+g*2]; fpkv[mt][1] = fpk[mt*8+g*2+1]; }
    #pragma unroll
    for (int mt = 0; mt < 4; ++mt) { r1pkv[mt][0] = r1pk[mt*8+g*2]; r1pkv[mt][1] = r1pk[mt*8+g*2+1]; }
    const unsigned int p3c = pk2(1.f, 0.f);

    f16x8 bd;                                   // dirs B-frag (kc=1 of color L1)
    #pragma unroll
    for (int j = 0; j < 8; ++j) bd[j] = (__fp16)0.f;
    if (g == 0) { bd[0] = (__fp16)dx; bd[1] = (__fp16)dy; bd[2] = (__fp16)dz; }

    float rr = 0.f, rg = 0.f, rb = 0.f;
    float carry = 0.f;

    #pragma unroll 1
    for (int chunk = 0; chunk < 2; ++chunk) {
        const int s  = (chunk << 6) + lane;
        const bool vs = (s < 127);
        const float tv = ttab[s];
        const float dist = dtab[s];

        float cx, cy, cz, fx, fy, fz;
        int x0, y0, z0;
        {
            #pragma clang fp contract(off)
            float px = ox + dx * tv;
            float py = oy + dy * tv;
            float pz = oz + dz * tv;
            float nrm = fmaxf(fabsf(px), fmaxf(fabsf(py), fabsf(pz)));
            if (nrm <= 1.0f) { cx = px; cy = py; cz = pz; }
            else {
                float t2 = 2.0f - 1.0f / nrm;
                cx = (t2 * px) / nrm; cy = (t2 * py) / nrm; cz = (t2 * pz) / nrm;
            }
            cx = cx * 0.5f; cy = cy * 0.5f; cz = cz * 0.5f;
            float gx = ((cx + 1.0f) * 128.0f - 1.0f) * 0.5f;
            float gy = ((cy + 1.0f) * 128.0f - 1.0f) * 0.5f;
            float gz = ((cz + 1.0f) * 128.0f - 1.0f) * 0.5f;
            float xf = floorf(gx), yf = floorf(gy), zf = floorf(gz);
            fx = gx - xf; fy = gy - yf; fz = gz - zf;
            x0 = (int)xf; y0 = (int)yf; z0 = (int)zf;
        }
        const bool fxp = fx > 0.f, fyp = fy > 0.f, fzp = fz > 0.f;
        bool m = gv(grid, z0,   y0,   x0)
             | (fxp             & gv(grid, z0,   y0,   x0+1))
             | (fyp             & gv(grid, z0,   y0+1, x0))
             | (fyp & fxp       & gv(grid, z0,   y0+1, x0+1))
             | (fzp             & gv(grid, z0+1, y0,   x0))
             | (fzp & fxp       & gv(grid, z0+1, y0,   x0+1))
             | (fzp & fyp       & gv(grid, z0+1, y0+1, x0))
             | (fzp & fyp & fxp & gv(grid, z0+1, y0+1, x0+1));
        m = m & vs;

        if (__ballot(m)) {
            // ---- coords hi/lo split (full f32 precision via MFMA) ----
            float xh = (float)(__fp16)cx, yh = (float)(__fp16)cy, zh = (float)(__fp16)cz;
            unsigned int q0 = pk2(xh, yh);
            unsigned int q1 = pk2(zh, cx - xh);
            unsigned int q2 = pk2(cy - yh, cz - zh);

            // ---- L1 via MFMA: H^T = W1e^T [c_hi;c_lo;1]^T  (K=32, bias folded) ----
            f16x8 bl1[4];
            #pragma unroll
            for (int nt = 0; nt < 4; ++nt) {
                int ad = (16*nt + c15) << 2;
                u32x4 bw;
                bw[0] = (unsigned int)__builtin_amdgcn_ds_bpermute(ad, (int)q0);
                bw[1] = (unsigned int)__builtin_amdgcn_ds_bpermute(ad, (int)q1);
                bw[2] = (unsigned int)__builtin_amdgcn_ds_bpermute(ad, (int)q2);
                bw[3] = p3c;      // k=6 -> 1.0 (bias row); garbage in g>0 lanes hits zero A cols
                bl1[nt] = __builtin_bit_cast(f16x8, bw);
            }
            #pragma unroll
            for (int mt = 0; mt < 4; ++mt) {
                f16x8 a = AF[(16+mt)*64 + lane];
                #pragma unroll
                for (int nt = 0; nt < 4; ++nt) {
                    f32x4 z = {0.f,0.f,0.f,0.f};
                    z = mfma16(a, bl1[nt], z);
                    u32x2 ww;
                    ww[0] = pkmax0(pk2(z[0], z[1]));
                    ww[1] = pkmax0(pk2(z[2], z[3]));
                    *(u32x2*)(ldsH + (16*nt + c15)*ROWB + 32*mt + 8*g) = ww;
                }
            }
            // ---- read H^T B-fragments ----
            f16x8 bh[4][2];
            #pragma unroll
            for (int nt = 0; nt < 4; ++nt)
                #pragma unroll
                for (int kc = 0; kc < 2; ++kc)
                    bh[nt][kc] = *(const f16x8*)(ldsH + (16*nt + c15)*ROWB + 64*kc + 16*g);

            // ---- L2: F^T = W2e^T H^T + b2e (row 32 = sigma_pre) ----
            #pragma unroll
            for (int mt = 0; mt < 3; ++mt) {
                f16x8 a0 = AF[(mt*2+0)*64 + lane];
                f16x8 a1 = AF[(mt*2+1)*64 + lane];
                f32x4 acc[4];
                #pragma unroll
                for (int nt = 0; nt < 4; ++nt) { f32x4 z = {0.f,0.f,0.f,0.f}; acc[nt] = z; }
                #pragma unroll
                for (int nt = 0; nt < 4; ++nt) acc[nt] = mfma16(a0, bh[nt][0], acc[nt]);
                #pragma unroll
                for (int nt = 0; nt < 4; ++nt) acc[nt] = mfma16(a1, bh[nt][1], acc[nt]);
                if (mt < 2) {
                    #pragma unroll
                    for (int nt = 0; nt < 4; ++nt) {
                        u32x2 ww;
                        ww[0] = pkadd(pk2(acc[nt][0], acc[nt][1]), fpkv[mt][0]);
                        ww[1] = pkadd(pk2(acc[nt][2], acc[nt][3]), fpkv[mt][1]);
                        *(u32x2*)(ldsH + (16*nt + c15)*ROWB + 32*mt + 8*g) = ww;
                    }
                } else if (g == 0) {
                    #pragma unroll
                    for (int nt = 0; nt < 4; ++nt)
                        ldsSig[16*nt + c15] = acc[nt][0] + b2e32;
                }
            }
            const float spre = ldsSig[lane];
            const float sp = fmaxf(spre, 0.f) + log1pf(expf(-fabsf(spre)));
            const float sigma = m ? sp : 0.f;
            const float al = -sigma * dist;

            // ---- inclusive wave scan of alpha_log ----
            float xs = al;
            #pragma unroll
            for (int d = 1; d < 64; d <<= 1) {
                float y = __shfl_up(xs, (unsigned)d, 64);
                if (lane >= d) xs += y;
            }
            const float total = __shfl(xs, 63, 64);
            const float trans = expf(carry + (xs - al));
            const float alpha = 1.0f - expf(al);
            const float w = trans * alpha;
            carry += total;

            const bool m2 = m & (w > 1e-4f);
            if (__ballot(m2)) {
                // ---- color L1: H2^T = relu(Wr1^T [F;dirs]^T + br1) ----
                f16x8 bf[4];
                #pragma unroll
                for (int nt = 0; nt < 4; ++nt)
                    bf[nt] = *(const f16x8*)(ldsH + (16*nt + c15)*ROWB + 16*g);
                #pragma unroll
                for (int mt = 0; mt < 4; ++mt) {
                    f16x8 a0 = AF[(6 + mt*2 + 0)*64 + lane];
                    f16x8 a1 = AF[(6 + mt*2 + 1)*64 + lane];
                    f32x4 acc[4];
                    #pragma unroll
                    for (int nt = 0; nt < 4; ++nt) { f32x4 z = {0.f,0.f,0.f,0.f}; acc[nt] = z; }
                    #pragma unroll
                    for (int nt = 0; nt < 4; ++nt) acc[nt] = mfma16(a0, bf[nt], acc[nt]);
                    #pragma unroll
                    for (int nt = 0; nt < 4; ++nt) acc[nt] = mfma16(a1, bd, acc[nt]);
                    #pragma unroll
                    for (int nt = 0; nt < 4; ++nt) {
                        u32x2 ww;
                        ww[0] = pkmax0(pkadd(pk2(acc[nt][0], acc[nt][1]), r1pkv[mt][0]));
                        ww[1] = pkmax0(pkadd(pk2(acc[nt][2], acc[nt][3]), r1pkv[mt][1]));
                        *(u32x2*)(ldsH + (16*nt + c15)*ROWB + 32*mt + 8*g) = ww;
                    }
                }
                // ---- color L2: RGB^T = Wr2^T H2^T ----
                f16x8 a0 = AF[14*64 + lane];
                f16x8 a1 = AF[15*64 + lane];
                f32x4 accr[4];
                #pragma unroll
                for (int nt = 0; nt < 4; ++nt) {
                    f16x8 q0c = *(const f16x8*)(ldsH + (16*nt + c15)*ROWB + 16*g);
                    f16x8 q1c = *(const f16x8*)(ldsH + (16*nt + c15)*ROWB + 64 + 16*g);
                    f32x4 z = {0.f,0.f,0.f,0.f};
                    z = mfma16(a0, q0c, z);
                    z = mfma16(a1, q1c, z);
                    accr[nt] = z;
                }
                if (g == 0) {
                    const float c0 = br2[0], c1 = br2[1], c2 = br2[2];
                    #pragma unroll
                    for (int nt = 0; nt < 4; ++nt) {
                        float* rp = ldsRgb + (16*nt + c15)*3;
                        rp[0] = accr[nt][0] + c0;
                        rp[1] = accr[nt][1] + c1;
                        rp[2] = accr[nt][2] + c2;
                    }
                }
                const float* rp = ldsRgb + lane*3;
                const float l0 = rp[0], l1 = rp[1], l2 = rp[2];
                const float wm = m2 ? w : 0.f;
                rr = fmaf(1.f/(1.f + expf(-l0)), wm, rr);
                rg = fmaf(1.f/(1.f + expf(-l1)), wm, rg);
                rb = fmaf(1.f/(1.f + expf(-l2)), wm, rb);
            }
            if (chunk == 0 && expf(carry) <= 5e-5f) break;
        }
    }

    #pragma unroll
    for (int d = 32; d > 0; d >>= 1) {
        rr += __shfl_xor(rr, d, 64);
        rg += __shfl_xor(rg, d, 64);
        rb += __shfl_xor(rb, d, 64);
    }
    if (lane == 0) {
        out[ray*3+0] = rr;
        out[ray*3+1] = rg;
        out[ray*3+2] = rb;
    }
}

extern "C" void kernel_launch(void* const* d_in, const int* in_sizes, int n_in,
                              void* d_out, int out_size, void* d_ws, size_t ws_size,
                              hipStream_t stream) {
    const float* rays_o = (const float*)d_in[0];
    const float* rays_d = (const float*)d_in[1];
    const float* grid   = (const float*)d_in[2];
    const float* W1  = (const float*)d_in[3];
    const float* b1  = (const float*)d_in[4];
    const float* W2  = (const float*)d_in[5];
    const float* b2  = (const float*)d_in[6];
    const float* Ws  = (const float*)d_in[7];
    const float* bs  = (const float*)d_in[8];
    const float* Wr1 = (const float*)d_in[9];
    const float* br1 = (const float*)d_in[10];
    const float* Wr2 = (const float*)d_in[11];
    const float* br2 = (const float*)d_in[12];
    float* out = (float*)d_out;
    unsigned char* ws = (unsigned char*)d_ws;

    prep<<<dim3(1), dim3(1024), 0, stream>>>(W1, b1, W2, b2, Ws, bs, Wr1, br1, Wr2, ws);
    nerf_render<<<dim3(16384/4), dim3(256), 0, stream>>>(
        rays_o, rays_d, grid, br2, ws, out);
}